// Round 8
// baseline (206.397 us; speedup 1.0000x reference)
//
#include <hip/hip_runtime.h>

// MultiHeadSelfAttention  B=2 S=2048 E=512 H=8 D=64, fp32 in/out.
// R14: BARRIER-FREE attn — K/V fragments read directly from global (L2).
//   Diagnosis chain: R11 (2 blk/CU, barriers) 35us; R13 (1 blk/CU, barriers)
//   66us = 2 sequential rounds -> attn is latency/BARRIER-bound, not LDS-BW
//   or VALU bound. R13's FETCH=6MB proves K/V lives in L2 (XCD swizzle works),
//   so LDS staging is pure overhead (guide lesson: don't stage L2-fit data).
//   New attn: 8 waves = (wq: 16 q-rows) x (ws: k-half). Wave loop has ZERO
//   __syncthreads: K-frags / V-frags loaded per-MFMA from kf/vt (16 rows x
//   64B halves -> 64B-granule coalescing, L1/L2-served); only in-wave Ps
//   roundtrip (lgkmcnt). Bias vector staged once (1 barrier at start); 1
//   barrier pair at end for the 2-way split-K combine. LDS 27KB, ~90 VGPR ->
//   4 waves/SIMD from 2 independent blocks, free-running.
//   proj / outproj: unchanged from R11 (passed).
// Layouts HW-verified (m89/m91/m120; confirmed R4-R13):
//   A[m=lane&15][k=quad*8+j], B[k=quad*8+j][n=lane&15], D[row=quad*4+reg][col=lane&15].
// Workspace: qf,kf fp16 + vt,ctx bf16 (4 x 4 MB) + Wob (512 KB).

#define B_ 2
#define S_ 2048
#define E_ 512
#define H_ 8
#define D_ 64

#define LOG2E 1.4426950408889634f
#define KEEP_BIAS (-92.332483f)        // -64 * log2(e)

typedef unsigned short ushort_t;
typedef __attribute__((ext_vector_type(8))) short short8;
typedef __attribute__((ext_vector_type(8))) _Float16 half8;
typedef __attribute__((ext_vector_type(4))) float f32x4;

__device__ __forceinline__ ushort_t f2bs(float x) {   // fp32 -> bf16 bits, RNE
    union { float f; unsigned int u; } a; a.f = x;
    unsigned int u = a.u;
    u += 0x7fffu + ((u >> 16) & 1u);
    return (ushort_t)(u >> 16);
}
__device__ __forceinline__ float bs2f(ushort_t h) {
    union { unsigned int u; float f; } a; a.u = ((unsigned int)h) << 16;
    return a.f;
}
__device__ __forceinline__ ushort_t f2hs(float x) {   // fp32 -> fp16 bits
    _Float16 h = (_Float16)x;
    ushort_t u; __builtin_memcpy(&u, &h, 2);
    return u;
}
// split 16 fp32 into bf16 hi + bf16 lo (residual)
__device__ __forceinline__ void split16(const float4* g, ushort_t* hi, ushort_t* lo) {
    #pragma unroll
    for (int q = 0; q < 4; ++q) {
        float4 f = g[q];
        float vv[4] = {f.x, f.y, f.z, f.w};
        #pragma unroll
        for (int j = 0; j < 4; ++j) {
            ushort_t h = f2bs(vv[j]);
            hi[q * 4 + j] = h;
            lo[q * 4 + j] = f2bs(vv[j] - bs2f(h));
        }
    }
}

// ---------------- Kernel 1: split-precision projection (+ Wob convert) ----------------
// blockIdx.y: 0=q 1=k 2=v 3=Wo->bf16 (bx<128 only).
__global__ void __launch_bounds__(256) proj_mfma(
    const float* __restrict__ quer, const float* __restrict__ keys,
    const float* __restrict__ vals, const float* __restrict__ Wv,
    const float* __restrict__ Wo,
    ushort_t* __restrict__ qf, ushort_t* __restrict__ kf,
    ushort_t* __restrict__ vt, ushort_t* __restrict__ Wob)
{
    __shared__ ushort_t Ah[64 * 72], Al[64 * 72];
    __shared__ ushort_t Bh[64 * 72], Bl[64 * 72];
    const int tens = blockIdx.y;
    const int bx = blockIdx.x;            // bh*32 + st
    const int t = threadIdx.x;

    if (tens == 3) {                      // one-time Wo fp32 -> bf16
        if (bx < 128) {
            int g = (bx * 256 + t) * 8;
            float4 f0 = *(const float4*)(Wo + g);
            float4 f1 = *(const float4*)(Wo + g + 4);
            ushort_t tmp[8] = {f2bs(f0.x), f2bs(f0.y), f2bs(f0.z), f2bs(f0.w),
                               f2bs(f1.x), f2bs(f1.y), f2bs(f1.z), f2bs(f1.w)};
            *(uint4*)&Wob[g] = *(uint4*)tmp;
        }
        return;
    }

    const float* src = tens == 0 ? quer : (tens == 1 ? keys : vals);
    const int st = bx & 31, bh = bx >> 5;
    const int b = bh >> 3, h = bh & 7;
    const int s0 = st * 64;

    {   // Wv -> Bh/Bl [e][d]   (B[k=d][n=e])
        int e = t >> 2, dg = (t & 3) * 16;
        ushort_t th[16], tl[16];
        split16((const float4*)(Wv + e * 64 + dg), th, tl);
        *(uint4*)&Bh[e * 72 + dg] = *(uint4*)th;  *(uint4*)&Bh[e * 72 + dg + 8] = *(uint4*)(th + 8);
        *(uint4*)&Bl[e * 72 + dg] = *(uint4*)tl;  *(uint4*)&Bl[e * 72 + dg + 8] = *(uint4*)(tl + 8);
    }
    {   // x rows (s0..s0+63) -> Ah/Al [s][d]
        int row = t >> 2, cg = (t & 3) * 16;
        const float* g = src + ((size_t)b * S_ + s0 + row) * 512 + h * 64 + cg;
        ushort_t th[16], tl[16];
        split16((const float4*)g, th, tl);
        *(uint4*)&Ah[row * 72 + cg] = *(uint4*)th;  *(uint4*)&Ah[row * 72 + cg + 8] = *(uint4*)(th + 8);
        *(uint4*)&Al[row * 72 + cg] = *(uint4*)tl;  *(uint4*)&Al[row * 72 + cg + 8] = *(uint4*)(tl + 8);
    }
    __syncthreads();

    const int w = t >> 6, lm = t & 15, quad = (t >> 4) & 3;
    f32x4 acc[4];
    #pragma unroll
    for (int nt = 0; nt < 4; ++nt) acc[nt] = (f32x4){0.f, 0.f, 0.f, 0.f};

    __builtin_amdgcn_s_setprio(1);
    #pragma unroll
    for (int kk = 0; kk < 2; ++kk) {
        short8 ah = *(const short8*)&Ah[(w * 16 + lm) * 72 + kk * 32 + quad * 8];
        short8 al = *(const short8*)&Al[(w * 16 + lm) * 72 + kk * 32 + quad * 8];
        #pragma unroll
        for (int nt = 0; nt < 4; ++nt) {
            short8 bh8 = *(const short8*)&Bh[(nt * 16 + lm) * 72 + kk * 32 + quad * 8];
            short8 bl8 = *(const short8*)&Bl[(nt * 16 + lm) * 72 + kk * 32 + quad * 8];
            acc[nt] = __builtin_amdgcn_mfma_f32_16x16x32_bf16(ah, bh8, acc[nt], 0, 0, 0);
            acc[nt] = __builtin_amdgcn_mfma_f32_16x16x32_bf16(al, bh8, acc[nt], 0, 0, 0);
            acc[nt] = __builtin_amdgcn_mfma_f32_16x16x32_bf16(ah, bl8, acc[nt], 0, 0, 0);
        }
    }
    __builtin_amdgcn_s_setprio(0);

    if (tens < 2) {       // q,k: store single fp16, layout (bh, s, d); q pre-scaled log2e
        ushort_t* dst = tens == 0 ? qf : kf;
        const float sc = tens == 0 ? LOG2E : 1.0f;
        #pragma unroll
        for (int nt = 0; nt < 4; ++nt) {
            #pragma unroll
            for (int r = 0; r < 4; ++r) {
                size_t addr = ((size_t)bh * S_ + s0 + w * 16 + quad * 4 + r) * 64 + nt * 16 + lm;
                dst[addr] = f2hs(acc[nt][r] * sc);
            }
        }
    } else {              // v: store bf16 transposed (bh, d, s) -> 8B packed stores
        #pragma unroll
        for (int nt = 0; nt < 4; ++nt) {
            unsigned int p0 = (unsigned int)f2bs(acc[nt][0]) | ((unsigned int)f2bs(acc[nt][1]) << 16);
            unsigned int p1 = (unsigned int)f2bs(acc[nt][2]) | ((unsigned int)f2bs(acc[nt][3]) << 16);
            uint2 pk; pk.x = p0; pk.y = p1;
            size_t addr = ((size_t)bh * 64 + nt * 16 + lm) * S_ + s0 + w * 16 + quad * 4;
            *(uint2*)&vt[addr] = pk;
        }
    }
}

// ---------------- Kernel 2: flash attention (barrier-free, L2-direct K/V) ----------------
__global__ void __launch_bounds__(512, 4) attn_mfma(
    const ushort_t* __restrict__ qf, const ushort_t* __restrict__ kf,
    const ushort_t* __restrict__ vt, const int* __restrict__ mask,
    ushort_t* __restrict__ ctx)
{
    __shared__ ushort_t Ps[8][16 * 72];       // per-wave 16x64 P, bf16; O-combine scratch after loop
    __shared__ float    biasL[S_];            // per-k bias: KEEP_BIAS or -1e30f; l-combine scratch

    const int bx0 = blockIdx.x;
    const int bx = (bx0 & 7) * 64 + (bx0 >> 3);   // XCD-contiguous remap (512 = 8*64, bijective)
    const int qt = bx & 31;
    const int bh = bx >> 5;
    const int b  = bh >> 3;
    const int t  = threadIdx.x;
    const int w  = t >> 6;                    // 0..7
    const int wq = w & 3;                     // q-subtile (16 rows)
    const int ws = w >> 2;                    // k-half 0..1
    const int lm = t & 15, quad = (t >> 4) & 3;
    const int lane = t & 63;
    const int q0 = qt * 64;

    // ---- stage bias vector once (the only pre-loop barrier) ----
    {
        int4 m4 = *(const int4*)&mask[b * S_ + t * 4];
        float4 bv;
        bv.x = m4.x ? KEEP_BIAS : -1e30f;
        bv.y = m4.y ? KEEP_BIAS : -1e30f;
        bv.z = m4.z ? KEEP_BIAS : -1e30f;
        bv.w = m4.w ? KEEP_BIAS : -1e30f;
        *(float4*)&biasL[t * 4] = bv;
    }

    // ---- Q B-frags (pre-scaled by log2e in proj) ----
    half8 aq0, aq1;
    {
        size_t qrow = ((size_t)bh * S_ + q0 + wq * 16 + lm) * 64 + quad * 8;
        aq0 = *(const half8*)&qf[qrow];
        aq1 = *(const half8*)&qf[qrow + 32];
    }
    short8 ones;
    #pragma unroll
    for (int j = 0; j < 8; ++j) ones[j] = (short)0x3F80;   // bf16 1.0

    // per-wave global fragment base pointers
    const ushort_t* kB = kf + ((size_t)bh * S_ + lm) * 64 + quad * 8;     // + (kc*64+nt*16)*64 (+32 for kk=1)
    const ushort_t* vB = vt + ((size_t)bh * 64 + lm) * S_ + quad * 8;     // + nt*16*S_ + kc*64 (+32)

    f32x4 acc[4];
    f32x4 accl = (f32x4){0.f, 0.f, 0.f, 0.f};
    #pragma unroll
    for (int nt = 0; nt < 4; ++nt) acc[nt] = (f32x4){0.f, 0.f, 0.f, 0.f};

    __syncthreads();                          // bias visible; last barrier before combine

    for (int kc = ws * 16; kc < ws * 16 + 16; ++kc) {
        // ---- S^T = K Q^T; K frags straight from global (L1/L2-served) ----
        #pragma unroll
        for (int nt = 0; nt < 4; ++nt) {
            const ushort_t* ka = kB + (size_t)(kc * 64 + nt * 16) * 64;
            half8 ak0 = *(const half8*)&ka[0];
            half8 ak1 = *(const half8*)&ka[32];
            f32x4 s = *(const f32x4*)&biasL[kc * 64 + nt * 16 + quad * 4];
            __builtin_amdgcn_s_setprio(1);
            s = __builtin_amdgcn_mfma_f32_16x16x32_f16(ak0, aq0, s, 0, 0, 0);
            s = __builtin_amdgcn_mfma_f32_16x16x32_f16(ak1, aq1, s, 0, 0, 0);
            __builtin_amdgcn_s_setprio(0);
            uint2 pkd;
            pkd.x = (unsigned int)f2bs(__builtin_amdgcn_exp2f(s[0])) |
                    ((unsigned int)f2bs(__builtin_amdgcn_exp2f(s[1])) << 16);
            pkd.y = (unsigned int)f2bs(__builtin_amdgcn_exp2f(s[2])) |
                    ((unsigned int)f2bs(__builtin_amdgcn_exp2f(s[3])) << 16);
            *(uint2*)&Ps[w][lm * 72 + nt * 16 + quad * 4] = pkd;
        }
        // (compiler inserts counted lgkmcnt for the in-wave Ps write->read dep)

        // ---- O += P V ; l += P . 1 ; V frags straight from global ----
        __builtin_amdgcn_s_setprio(1);
        #pragma unroll
        for (int kk = 0; kk < 2; ++kk) {
            short8 ap = *(const short8*)&Ps[w][lm * 72 + kk * 32 + quad * 8];
            #pragma unroll
            for (int nt = 0; nt < 4; ++nt) {
                short8 bv = *(const short8*)&vB[(size_t)(nt * 16) * S_ + kc * 64 + kk * 32];
                acc[nt] = __builtin_amdgcn_mfma_f32_16x16x32_bf16(ap, bv, acc[nt], 0, 0, 0);
            }
            accl = __builtin_amdgcn_mfma_f32_16x16x32_bf16(ap, ones, accl, 0, 0, 0);
        }
        __builtin_amdgcn_s_setprio(0);
    }

    // ---- 2-way split-K combine via LDS (reuse Ps for O, biasL for l) ----
    float* cfO = (float*)Ps;                  // 4 wq x 64 lanes x 17 floats = 17.4 KB <= 18.4 KB
    float* cfL = biasL;                       // 4 x 64 x 5 = 5.1 KB <= 8 KB
    __syncthreads();                          // all waves done with biasL + Ps
    if (ws == 1) {
        const int bO = (wq * 64 + lane) * 17;
        const int bL = (wq * 64 + lane) * 5;
        #pragma unroll
        for (int nt = 0; nt < 4; ++nt)
            #pragma unroll
            for (int r = 0; r < 4; ++r) cfO[bO + nt * 4 + r] = acc[nt][r];
        #pragma unroll
        for (int r = 0; r < 4; ++r) cfL[bL + r] = accl[r];
    }
    __syncthreads();
    if (ws == 0) {
        const int bO = (wq * 64 + lane) * 17;
        const int bL = (wq * 64 + lane) * 5;
        const int h = bh & 7;
        #pragma unroll
        for (int r = 0; r < 4; ++r) {
            float l = accl[r] + cfL[bL + r];
            float inv = 1.f / l;
            int s = q0 + wq * 16 + quad * 4 + r;
            #pragma unroll
            for (int nt = 0; nt < 4; ++nt) {
                float o = acc[nt][r] + cfO[bO + nt * 4 + r];
                ctx[((size_t)b * S_ + s) * E_ + h * D_ + nt * 16 + lm] = f2bs(o * inv);
            }
        }
    }
}

// ---------------- Kernel 3: out = ctx @ Wo^T + bo (split-K wave halves) ----------------
__global__ void __launch_bounds__(512, 4) outproj_mfma(
    const ushort_t* __restrict__ ctx, const ushort_t* __restrict__ Wob,
    const float* __restrict__ bo, float* __restrict__ out)
{
    __shared__ ushort_t sm[4][64 * 72];       // A0,A1,B0,B1 ; reused as f32 combine scratch
    const int m0 = blockIdx.x * 64, n0 = blockIdx.y * 64;
    const int t = threadIdx.x;
    const int w = t >> 6, wq = w & 3, wk = w >> 2;
    const int lm = t & 15, quad = (t >> 4) & 3;
    const int srow = t >> 3, scg = (t & 7) * 8;

    const size_t abase = (size_t)(m0 + srow) * E_ + scg;   // + ktile*64
    const size_t bbase = (size_t)(n0 + srow) * E_ + scg;

    f32x4 acc[4];
    #pragma unroll
    for (int nt = 0; nt < 4; ++nt) acc[nt] = (f32x4){0.f, 0.f, 0.f, 0.f};

    // prologue: stage superstep 0 (k-tiles 0 and 4)
    *(uint4*)&sm[0][srow * 72 + scg] = *(const uint4*)&ctx[abase];
    *(uint4*)&sm[1][srow * 72 + scg] = *(const uint4*)&ctx[abase + 256];
    *(uint4*)&sm[2][srow * 72 + scg] = *(const uint4*)&Wob[bbase];
    *(uint4*)&sm[3][srow * 72 + scg] = *(const uint4*)&Wob[bbase + 256];
    __syncthreads();

    const ushort_t* Ac = sm[wk];
    const ushort_t* Bc = sm[2 + wk];

    for (int is = 0; is < 4; ++is) {
        const bool pf = is < 3;
        uint4 pa0, pa1, pb0, pb1;
        if (pf) {
            pa0 = *(const uint4*)&ctx[abase + (size_t)(is + 1) * 64];
            pa1 = *(const uint4*)&ctx[abase + 256 + (size_t)(is + 1) * 64];
            pb0 = *(const uint4*)&Wob[bbase + (size_t)(is + 1) * 64];
            pb1 = *(const uint4*)&Wob[bbase + 256 + (size_t)(is + 1) * 64];
        }

        __builtin_amdgcn_s_setprio(1);
        #pragma unroll
        for (int kk = 0; kk < 2; ++kk) {
            short8 a = *(const short8*)&Ac[(wq * 16 + lm) * 72 + kk * 32 + quad * 8];
            #pragma unroll
            for (int nt = 0; nt < 4; ++nt) {
                short8 bb = *(const short8*)&Bc[(nt * 16 + lm) * 72 + kk * 32 + quad * 8];
                acc[nt] = __builtin_amdgcn_mfma_f32_16x16x32_bf16(a, bb, acc[nt], 0, 0, 0);
            }
        }
        __builtin_amdgcn_s_setprio(0);

        __syncthreads();                       // all waves done reading tiles
        if (pf) {
            *(uint4*)&sm[0][srow * 72 + scg] = pa0;
            *(uint4*)&sm[1][srow * 72 + scg] = pa1;
            *(uint4*)&sm[2][srow * 72 + scg] = pb0;
            *(uint4*)&sm[3][srow * 72 + scg] = pb1;
            __syncthreads();
        }
    }

    // ---- combine k-halves (fp32, reuse sm; 36 KB >= 18.4 KB needed) ----
    float* cf = (float*)sm;
    const int lane = t & 63;
    if (wk == 1) {
        const int base = (wq * 64 + lane) * 18;
        #pragma unroll
        for (int nt = 0; nt < 4; ++nt) {
            #pragma unroll
            for (int r = 0; r < 4; r += 2) {
                float2 v2; v2.x = acc[nt][r]; v2.y = acc[nt][r + 1];
                *(float2*)&cf[base + nt * 4 + r] = v2;
            }
        }
    }
    __syncthreads();
    if (wk == 0) {
        const int base = (wq * 64 + lane) * 18;
        #pragma unroll
        for (int nt = 0; nt < 4; ++nt) {
            float bias = bo[n0 + nt * 16 + lm];
            #pragma unroll
            for (int r = 0; r < 4; ++r) {
                int m = m0 + wq * 16 + quad * 4 + r;
                out[(size_t)m * E_ + n0 + nt * 16 + lm] =
                    acc[nt][r] + cf[base + nt * 4 + r] + bias;
            }
        }
    }
}

extern "C" void kernel_launch(void* const* d_in, const int* in_sizes, int n_in,
                              void* d_out, int out_size, void* d_ws, size_t ws_size,
                              hipStream_t stream) {
    const float* vals = (const float*)d_in[0];
    const float* keys = (const float*)d_in[1];
    const float* quer = (const float*)d_in[2];
    const int*   mask = (const int*)d_in[3];
    const float* Wv   = (const float*)d_in[4];
    const float* Wo   = (const float*)d_in[5];
    const float* bo   = (const float*)d_in[6];
    float* out = (float*)d_out;

    const size_t N = (size_t)B_ * H_ * S_ * D_;   // 2097152
    ushort_t* ws  = (ushort_t*)d_ws;
    ushort_t* qf  = ws;                 // fp16 (q pre-scaled by log2e)
    ushort_t* kf  = ws + N;             // fp16
    ushort_t* vt  = ws + 2 * N;         // bf16, transposed (bh, d, s)
    ushort_t* ctx = ws + 3 * N;         // bf16
    ushort_t* Wob = ws + 4 * N;         // bf16, 512*512

    proj_mfma<<<dim3(B_ * H_ * (S_ / 64), 4), 256, 0, stream>>>(
        quer, keys, vals, Wv, Wo, qf, kf, vt, Wob);
    attn_mfma<<<B_ * H_ * (S_ / 64), 512, 0, stream>>>(qf, kf, vt, mask, ctx);
    outproj_mfma<<<dim3((B_ * S_) / 64, E_ / 64), 512, 0, stream>>>(ctx, Wob, bo, out);
}

// Round 9
// 138.976 us; speedup vs baseline: 1.4851x; 1.4851x over previous
//
#include <hip/hip_runtime.h>

// MultiHeadSelfAttention  B=2 S=2048 E=512 H=8 D=64, fp32 in/out.
// R15: fat waves at 2-blocks/CU LDS budget — the synthesis of R11-R14:
//   R11 (35us) = LDS-issue-bound: 4 wq-waves re-read identical K/V frags (4x).
//   R12 fat-wave cut was right (FETCH 6x down) but spilled (118MB writes).
//   R13 fixed spill but 109KB LDS -> 1 blk/CU -> 2 serial rounds (66us).
//   R14 global-direct -> latency-bound, 120us (no prefetch distance).
//   R15: 256-thr block, 4 waves = (wq: 32 q-rows) x (ws: 2-way k-parity).
//   One K/V frag ds_read feeds 2 MFMAs; LDS = Ks[2]+Vt[2]+Ps[4][32]+mb =
//   55.8KB <= 64KB -> 2 blocks/CU co-reside; per-CU LDS issue ~1.64x down vs
//   R11. Staging via NAMED prefetch regs (R13 lesson), R11 control flow:
//   stage 2 tiles/superstep, 16 supersteps, 1 barrier pair each. 2-way
//   combine via Ks/Vt scratch (stride-17/5). XCD-bijective block swizzle.
//   proj / outproj: unchanged from R11 (passed).
// Layouts HW-verified (m89/m91/m120; confirmed R4-R14):
//   A[m=lane&15][k=quad*8+j], B[k=quad*8+j][n=lane&15], D[row=quad*4+reg][col=lane&15].
// LDS stride 72 shorts (144 B) -> 16B-aligned b128.
// Workspace: qf,kf fp16 + vt,ctx bf16 (4 x 4 MB) + Wob (512 KB).

#define B_ 2
#define S_ 2048
#define E_ 512
#define H_ 8
#define D_ 64

#define LOG2E 1.4426950408889634f
#define KEEP_BIAS (-92.332483f)        // -64 * log2(e)

typedef unsigned short ushort_t;
typedef __attribute__((ext_vector_type(8))) short short8;
typedef __attribute__((ext_vector_type(8))) _Float16 half8;
typedef __attribute__((ext_vector_type(4))) float f32x4;

__device__ __forceinline__ ushort_t f2bs(float x) {   // fp32 -> bf16 bits, RNE
    union { float f; unsigned int u; } a; a.f = x;
    unsigned int u = a.u;
    u += 0x7fffu + ((u >> 16) & 1u);
    return (ushort_t)(u >> 16);
}
__device__ __forceinline__ float bs2f(ushort_t h) {
    union { unsigned int u; float f; } a; a.u = ((unsigned int)h) << 16;
    return a.f;
}
__device__ __forceinline__ ushort_t f2hs(float x) {   // fp32 -> fp16 bits
    _Float16 h = (_Float16)x;
    ushort_t u; __builtin_memcpy(&u, &h, 2);
    return u;
}
// split 16 fp32 into bf16 hi + bf16 lo (residual)
__device__ __forceinline__ void split16(const float4* g, ushort_t* hi, ushort_t* lo) {
    #pragma unroll
    for (int q = 0; q < 4; ++q) {
        float4 f = g[q];
        float vv[4] = {f.x, f.y, f.z, f.w};
        #pragma unroll
        for (int j = 0; j < 4; ++j) {
            ushort_t h = f2bs(vv[j]);
            hi[q * 4 + j] = h;
            lo[q * 4 + j] = f2bs(vv[j] - bs2f(h));
        }
    }
}

// ---------------- Kernel 1: split-precision projection (+ Wob convert) ----------------
// blockIdx.y: 0=q 1=k 2=v 3=Wo->bf16 (bx<128 only).
__global__ void __launch_bounds__(256) proj_mfma(
    const float* __restrict__ quer, const float* __restrict__ keys,
    const float* __restrict__ vals, const float* __restrict__ Wv,
    const float* __restrict__ Wo,
    ushort_t* __restrict__ qf, ushort_t* __restrict__ kf,
    ushort_t* __restrict__ vt, ushort_t* __restrict__ Wob)
{
    __shared__ ushort_t Ah[64 * 72], Al[64 * 72];
    __shared__ ushort_t Bh[64 * 72], Bl[64 * 72];
    const int tens = blockIdx.y;
    const int bx = blockIdx.x;            // bh*32 + st
    const int t = threadIdx.x;

    if (tens == 3) {                      // one-time Wo fp32 -> bf16
        if (bx < 128) {
            int g = (bx * 256 + t) * 8;
            float4 f0 = *(const float4*)(Wo + g);
            float4 f1 = *(const float4*)(Wo + g + 4);
            ushort_t tmp[8] = {f2bs(f0.x), f2bs(f0.y), f2bs(f0.z), f2bs(f0.w),
                               f2bs(f1.x), f2bs(f1.y), f2bs(f1.z), f2bs(f1.w)};
            *(uint4*)&Wob[g] = *(uint4*)tmp;
        }
        return;
    }

    const float* src = tens == 0 ? quer : (tens == 1 ? keys : vals);
    const int st = bx & 31, bh = bx >> 5;
    const int b = bh >> 3, h = bh & 7;
    const int s0 = st * 64;

    {   // Wv -> Bh/Bl [e][d]   (B[k=d][n=e])
        int e = t >> 2, dg = (t & 3) * 16;
        ushort_t th[16], tl[16];
        split16((const float4*)(Wv + e * 64 + dg), th, tl);
        *(uint4*)&Bh[e * 72 + dg] = *(uint4*)th;  *(uint4*)&Bh[e * 72 + dg + 8] = *(uint4*)(th + 8);
        *(uint4*)&Bl[e * 72 + dg] = *(uint4*)tl;  *(uint4*)&Bl[e * 72 + dg + 8] = *(uint4*)(tl + 8);
    }
    {   // x rows (s0..s0+63) -> Ah/Al [s][d]
        int row = t >> 2, cg = (t & 3) * 16;
        const float* g = src + ((size_t)b * S_ + s0 + row) * 512 + h * 64 + cg;
        ushort_t th[16], tl[16];
        split16((const float4*)g, th, tl);
        *(uint4*)&Ah[row * 72 + cg] = *(uint4*)th;  *(uint4*)&Ah[row * 72 + cg + 8] = *(uint4*)(th + 8);
        *(uint4*)&Al[row * 72 + cg] = *(uint4*)tl;  *(uint4*)&Al[row * 72 + cg + 8] = *(uint4*)(tl + 8);
    }
    __syncthreads();

    const int w = t >> 6, lm = t & 15, quad = (t >> 4) & 3;
    f32x4 acc[4];
    #pragma unroll
    for (int nt = 0; nt < 4; ++nt) acc[nt] = (f32x4){0.f, 0.f, 0.f, 0.f};

    __builtin_amdgcn_s_setprio(1);
    #pragma unroll
    for (int kk = 0; kk < 2; ++kk) {
        short8 ah = *(const short8*)&Ah[(w * 16 + lm) * 72 + kk * 32 + quad * 8];
        short8 al = *(const short8*)&Al[(w * 16 + lm) * 72 + kk * 32 + quad * 8];
        #pragma unroll
        for (int nt = 0; nt < 4; ++nt) {
            short8 bh8 = *(const short8*)&Bh[(nt * 16 + lm) * 72 + kk * 32 + quad * 8];
            short8 bl8 = *(const short8*)&Bl[(nt * 16 + lm) * 72 + kk * 32 + quad * 8];
            acc[nt] = __builtin_amdgcn_mfma_f32_16x16x32_bf16(ah, bh8, acc[nt], 0, 0, 0);
            acc[nt] = __builtin_amdgcn_mfma_f32_16x16x32_bf16(al, bh8, acc[nt], 0, 0, 0);
            acc[nt] = __builtin_amdgcn_mfma_f32_16x16x32_bf16(ah, bl8, acc[nt], 0, 0, 0);
        }
    }
    __builtin_amdgcn_s_setprio(0);

    if (tens < 2) {       // q,k: store single fp16, layout (bh, s, d); q pre-scaled log2e
        ushort_t* dst = tens == 0 ? qf : kf;
        const float sc = tens == 0 ? LOG2E : 1.0f;
        #pragma unroll
        for (int nt = 0; nt < 4; ++nt) {
            #pragma unroll
            for (int r = 0; r < 4; ++r) {
                size_t addr = ((size_t)bh * S_ + s0 + w * 16 + quad * 4 + r) * 64 + nt * 16 + lm;
                dst[addr] = f2hs(acc[nt][r] * sc);
            }
        }
    } else {              // v: store bf16 transposed (bh, d, s) -> 8B packed stores
        #pragma unroll
        for (int nt = 0; nt < 4; ++nt) {
            unsigned int p0 = (unsigned int)f2bs(acc[nt][0]) | ((unsigned int)f2bs(acc[nt][1]) << 16);
            unsigned int p1 = (unsigned int)f2bs(acc[nt][2]) | ((unsigned int)f2bs(acc[nt][3]) << 16);
            uint2 pk; pk.x = p0; pk.y = p1;
            size_t addr = ((size_t)bh * 64 + nt * 16 + lm) * S_ + s0 + w * 16 + quad * 4;
            *(uint2*)&vt[addr] = pk;
        }
    }
}

// ---------------- Kernel 2: flash attention (fat waves, 2 blocks/CU) ----------------
// 4 waves: wq = w&1 (32 q-rows), ws = w>>1 (k-parity). Stage roles:
// w=0:(K,par0) w=1:(K,par1) w=2:(V,par0) w=3:(V,par1). 16 supersteps x 2 tiles.
__global__ void __launch_bounds__(256, 2) attn_mfma(
    const ushort_t* __restrict__ qf, const ushort_t* __restrict__ kf,
    const ushort_t* __restrict__ vt, const int* __restrict__ mask,
    ushort_t* __restrict__ ctx)
{
    __shared__ ushort_t Ks[2][64 * 72];       // fp16 K tiles [k][d] per parity; O-combine scratch after loop
    __shared__ ushort_t Vt[2][64 * 72];       // bf16 V tiles [d][k]; l-combine scratch after loop
    __shared__ ushort_t Ps[4][32 * 72];       // per-wave 32x64 P, bf16
    __shared__ float    mb[2][64];            // KEEP_BIAS or -1e30f, per parity

    const int bx0 = blockIdx.x;
    const int bx = (bx0 & 7) * 64 + (bx0 >> 3);   // XCD-contiguous remap (512 = 8*64, bijective)
    const int qt = bx & 31;
    const int bh = bx >> 5;
    const int b  = bh >> 3;
    const int t  = threadIdx.x;
    const int w  = t >> 6;                    // 0..3
    const int wq = w & 1;                     // q-group (32 rows)
    const int ws = w >> 1;                    // k-parity this wave computes
    const int lm = t & 15, quad = (t >> 4) & 3;
    const int lane = t & 63;
    const int q0 = qt * 64;

    // ---- staging role: parity stW, K or V; 64 lanes x 128B/row = 8 uint4 ----
    const int stW = w & 1;
    const bool isV = w >= 2;
    const size_t kst0 = ((size_t)bh * S_ + stW * 64 + lane) * 64;   // += is*8192
    const size_t vst0 = ((size_t)bh * 64 + lane) * S_ + stW * 64;   // += is*128
    ushort_t* sdst = isV ? &Vt[stW][lane * 72] : &Ks[stW][lane * 72];
    const ushort_t* sgl = isV ? vt : kf;
    const size_t sg0 = isV ? vst0 : kst0;
    const size_t sgstep = isV ? 128 : 8192;

    // ---- Q B-frags for both q-groups (pre-scaled by log2e in proj) ----
    half8 aq00, aq01, aq10, aq11;
    {
        size_t qr0 = ((size_t)bh * S_ + q0 + wq * 32 + lm) * 64 + quad * 8;
        size_t qr1 = ((size_t)bh * S_ + q0 + wq * 32 + 16 + lm) * 64 + quad * 8;
        aq00 = *(const half8*)&qf[qr0];
        aq01 = *(const half8*)&qf[qr0 + 32];
        aq10 = *(const half8*)&qf[qr1];
        aq11 = *(const half8*)&qf[qr1 + 32];
    }
    short8 ones;
    #pragma unroll
    for (int j = 0; j < 8; ++j) ones[j] = (short)0x3F80;   // bf16 1.0

    f32x4 acc[2][4];
    f32x4 accl[2];
    #pragma unroll
    for (int qg = 0; qg < 2; ++qg) {
        accl[qg] = (f32x4){0.f, 0.f, 0.f, 0.f};
        #pragma unroll
        for (int nt = 0; nt < 4; ++nt) acc[qg][nt] = (f32x4){0.f, 0.f, 0.f, 0.f};
    }

    // ---- prologue: stage tiles 0,1 (parities) + mask ----
    {
        uint4 p0 = *(const uint4*)&sgl[sg0];
        uint4 p1 = *(const uint4*)&sgl[sg0 + 8];
        uint4 p2 = *(const uint4*)&sgl[sg0 + 16];
        uint4 p3 = *(const uint4*)&sgl[sg0 + 24];
        uint4 p4 = *(const uint4*)&sgl[sg0 + 32];
        uint4 p5 = *(const uint4*)&sgl[sg0 + 40];
        uint4 p6 = *(const uint4*)&sgl[sg0 + 48];
        uint4 p7 = *(const uint4*)&sgl[sg0 + 56];
        *(uint4*)&sdst[0]  = p0;  *(uint4*)&sdst[8]  = p1;
        *(uint4*)&sdst[16] = p2;  *(uint4*)&sdst[24] = p3;
        *(uint4*)&sdst[32] = p4;  *(uint4*)&sdst[40] = p5;
        *(uint4*)&sdst[48] = p6;  *(uint4*)&sdst[56] = p7;
        if (t < 128) mb[t >> 6][t & 63] = mask[b * S_ + t] ? KEEP_BIAS : -1e30f;
    }
    __syncthreads();

    for (int is = 0; is < 16; ++is) {
        const bool pf = is < 15;

        // ---- prefetch next superstep's tile (this wave's role); NAMED regs ----
        uint4 s0r, s1r, s2r, s3r, s4r, s5r, s6r, s7r; int mnx = 0;
        if (pf) {
            size_t g = sg0 + (size_t)(is + 1) * sgstep;
            s0r = *(const uint4*)&sgl[g];
            s1r = *(const uint4*)&sgl[g + 8];
            s2r = *(const uint4*)&sgl[g + 16];
            s3r = *(const uint4*)&sgl[g + 24];
            s4r = *(const uint4*)&sgl[g + 32];
            s5r = *(const uint4*)&sgl[g + 40];
            s6r = *(const uint4*)&sgl[g + 48];
            s7r = *(const uint4*)&sgl[g + 56];
            if (t < 128) mnx = mask[b * S_ + (is + 1) * 128 + t];
        }

        const ushort_t* Kc = Ks[ws];
        const ushort_t* Vc = Vt[ws];

        // ---- S^T = K Q^T for both q-groups; K frag read once, used twice.
        //      acc init = mask bias; p = exp2(s); pack; b64 P write per (qg,nt). ----
        #pragma unroll
        for (int nt = 0; nt < 4; ++nt) {
            f32x4 binit = *(const f32x4*)&mb[ws][nt * 16 + quad * 4];
            f32x4 s0v = binit, s1v = binit;
            __builtin_amdgcn_s_setprio(1);
            #pragma unroll
            for (int kk = 0; kk < 2; ++kk) {
                half8 ak = *(const half8*)&Kc[(nt * 16 + lm) * 72 + kk * 32 + quad * 8];
                half8 aqa = kk ? aq01 : aq00;
                half8 aqb = kk ? aq11 : aq10;
                s0v = __builtin_amdgcn_mfma_f32_16x16x32_f16(ak, aqa, s0v, 0, 0, 0);
                s1v = __builtin_amdgcn_mfma_f32_16x16x32_f16(ak, aqb, s1v, 0, 0, 0);
            }
            __builtin_amdgcn_s_setprio(0);
            uint2 p0d, p1d;
            p0d.x = (unsigned int)f2bs(__builtin_amdgcn_exp2f(s0v[0])) |
                    ((unsigned int)f2bs(__builtin_amdgcn_exp2f(s0v[1])) << 16);
            p0d.y = (unsigned int)f2bs(__builtin_amdgcn_exp2f(s0v[2])) |
                    ((unsigned int)f2bs(__builtin_amdgcn_exp2f(s0v[3])) << 16);
            p1d.x = (unsigned int)f2bs(__builtin_amdgcn_exp2f(s1v[0])) |
                    ((unsigned int)f2bs(__builtin_amdgcn_exp2f(s1v[1])) << 16);
            p1d.y = (unsigned int)f2bs(__builtin_amdgcn_exp2f(s1v[2])) |
                    ((unsigned int)f2bs(__builtin_amdgcn_exp2f(s1v[3])) << 16);
            *(uint2*)&Ps[w][(lm) * 72 + nt * 16 + quad * 4]      = p0d;
            *(uint2*)&Ps[w][(16 + lm) * 72 + nt * 16 + quad * 4] = p1d;
        }
        // (compiler inserts counted lgkmcnt for the in-wave Ps write->read dep)

        // ---- O += P V ; l += P . 1 ; V frag read once, used twice ----
        __builtin_amdgcn_s_setprio(1);
        #pragma unroll
        for (int kk = 0; kk < 2; ++kk) {
            short8 ap0 = *(const short8*)&Ps[w][(lm) * 72 + kk * 32 + quad * 8];
            short8 ap1 = *(const short8*)&Ps[w][(16 + lm) * 72 + kk * 32 + quad * 8];
            #pragma unroll
            for (int nt = 0; nt < 4; ++nt) {
                short8 bv = *(const short8*)&Vc[(nt * 16 + lm) * 72 + kk * 32 + quad * 8];
                acc[0][nt] = __builtin_amdgcn_mfma_f32_16x16x32_bf16(ap0, bv, acc[0][nt], 0, 0, 0);
                acc[1][nt] = __builtin_amdgcn_mfma_f32_16x16x32_bf16(ap1, bv, acc[1][nt], 0, 0, 0);
            }
            accl[0] = __builtin_amdgcn_mfma_f32_16x16x32_bf16(ap0, ones, accl[0], 0, 0, 0);
            accl[1] = __builtin_amdgcn_mfma_f32_16x16x32_bf16(ap1, ones, accl[1], 0, 0, 0);
        }
        __builtin_amdgcn_s_setprio(0);

        __syncthreads();                       // all waves done reading tiles
        if (pf) {
            *(uint4*)&sdst[0]  = s0r;  *(uint4*)&sdst[8]  = s1r;
            *(uint4*)&sdst[16] = s2r;  *(uint4*)&sdst[24] = s3r;
            *(uint4*)&sdst[32] = s4r;  *(uint4*)&sdst[40] = s5r;
            *(uint4*)&sdst[48] = s6r;  *(uint4*)&sdst[56] = s7r;
            if (t < 128) mb[t >> 6][t & 63] = mnx ? KEEP_BIAS : -1e30f;
            __syncthreads();                   // staged tiles visible
        }
    }

    // ---- 2-way split-K combine via LDS (reuse Ks for O, Vt for l) ----
    float* cfO = (float*)Ks;                  // 4608 floats; need 4*64*17 = 4352
    float* cfL = (float*)Vt;                  // need 4*64*5 = 1280
    __syncthreads();                          // all waves done with tiles
    if (ws == 1) {
        #pragma unroll
        for (int qg = 0; qg < 2; ++qg) {
            const int sid = wq * 2 + qg;
            const int bO = (sid * 64 + lane) * 17;
            const int bL = (sid * 64 + lane) * 5;
            #pragma unroll
            for (int nt = 0; nt < 4; ++nt)
                #pragma unroll
                for (int r = 0; r < 4; ++r) cfO[bO + nt * 4 + r] = acc[qg][nt][r];
            #pragma unroll
            for (int r = 0; r < 4; ++r) cfL[bL + r] = accl[qg][r];
        }
    }
    __syncthreads();
    if (ws == 0) {
        const int h = bh & 7;
        #pragma unroll
        for (int qg = 0; qg < 2; ++qg) {
            const int sid = wq * 2 + qg;
            const int bO = (sid * 64 + lane) * 17;
            const int bL = (sid * 64 + lane) * 5;
            #pragma unroll
            for (int r = 0; r < 4; ++r) {
                float l = accl[qg][r] + cfL[bL + r];
                float inv = 1.f / l;
                int s = q0 + wq * 32 + qg * 16 + quad * 4 + r;
                #pragma unroll
                for (int nt = 0; nt < 4; ++nt) {
                    float o = acc[qg][nt][r] + cfO[bO + nt * 4 + r];
                    ctx[((size_t)b * S_ + s) * E_ + h * D_ + nt * 16 + lm] = f2bs(o * inv);
                }
            }
        }
    }
}

// ---------------- Kernel 3: out = ctx @ Wo^T + bo (split-K wave halves) ----------------
__global__ void __launch_bounds__(512, 4) outproj_mfma(
    const ushort_t* __restrict__ ctx, const ushort_t* __restrict__ Wob,
    const float* __restrict__ bo, float* __restrict__ out)
{
    __shared__ ushort_t sm[4][64 * 72];       // A0,A1,B0,B1 ; reused as f32 combine scratch
    const int m0 = blockIdx.x * 64, n0 = blockIdx.y * 64;
    const int t = threadIdx.x;
    const int w = t >> 6, wq = w & 3, wk = w >> 2;
    const int lm = t & 15, quad = (t >> 4) & 3;
    const int srow = t >> 3, scg = (t & 7) * 8;

    const size_t abase = (size_t)(m0 + srow) * E_ + scg;   // + ktile*64
    const size_t bbase = (size_t)(n0 + srow) * E_ + scg;

    f32x4 acc[4];
    #pragma unroll
    for (int nt = 0; nt < 4; ++nt) acc[nt] = (f32x4){0.f, 0.f, 0.f, 0.f};

    // prologue: stage superstep 0 (k-tiles 0 and 4)
    *(uint4*)&sm[0][srow * 72 + scg] = *(const uint4*)&ctx[abase];
    *(uint4*)&sm[1][srow * 72 + scg] = *(const uint4*)&ctx[abase + 256];
    *(uint4*)&sm[2][srow * 72 + scg] = *(const uint4*)&Wob[bbase];
    *(uint4*)&sm[3][srow * 72 + scg] = *(const uint4*)&Wob[bbase + 256];
    __syncthreads();

    const ushort_t* Ac = sm[wk];
    const ushort_t* Bc = sm[2 + wk];

    for (int is = 0; is < 4; ++is) {
        const bool pf = is < 3;
        uint4 pa0, pa1, pb0, pb1;
        if (pf) {
            pa0 = *(const uint4*)&ctx[abase + (size_t)(is + 1) * 64];
            pa1 = *(const uint4*)&ctx[abase + 256 + (size_t)(is + 1) * 64];
            pb0 = *(const uint4*)&Wob[bbase + (size_t)(is + 1) * 64];
            pb1 = *(const uint4*)&Wob[bbase + 256 + (size_t)(is + 1) * 64];
        }

        __builtin_amdgcn_s_setprio(1);
        #pragma unroll
        for (int kk = 0; kk < 2; ++kk) {
            short8 a = *(const short8*)&Ac[(wq * 16 + lm) * 72 + kk * 32 + quad * 8];
            #pragma unroll
            for (int nt = 0; nt < 4; ++nt) {
                short8 bb = *(const short8*)&Bc[(nt * 16 + lm) * 72 + kk * 32 + quad * 8];
                acc[nt] = __builtin_amdgcn_mfma_f32_16x16x32_bf16(a, bb, acc[nt], 0, 0, 0);
            }
        }
        __builtin_amdgcn_s_setprio(0);

        __syncthreads();                       // all waves done reading tiles
        if (pf) {
            *(uint4*)&sm[0][srow * 72 + scg] = pa0;
            *(uint4*)&sm[1][srow * 72 + scg] = pa1;
            *(uint4*)&sm[2][srow * 72 + scg] = pb0;
            *(uint4*)&sm[3][srow * 72 + scg] = pb1;
            __syncthreads();
        }
    }

    // ---- combine k-halves (fp32, reuse sm; 36 KB >= 18.4 KB needed) ----
    float* cf = (float*)sm;
    const int lane = t & 63;
    if (wk == 1) {
        const int base = (wq * 64 + lane) * 18;
        #pragma unroll
        for (int nt = 0; nt < 4; ++nt) {
            #pragma unroll
            for (int r = 0; r < 4; r += 2) {
                float2 v2; v2.x = acc[nt][r]; v2.y = acc[nt][r + 1];
                *(float2*)&cf[base + nt * 4 + r] = v2;
            }
        }
    }
    __syncthreads();
    if (wk == 0) {
        const int base = (wq * 64 + lane) * 18;
        #pragma unroll
        for (int nt = 0; nt < 4; ++nt) {
            float bias = bo[n0 + nt * 16 + lm];
            #pragma unroll
            for (int r = 0; r < 4; ++r) {
                int m = m0 + wq * 16 + quad * 4 + r;
                out[(size_t)m * E_ + n0 + nt * 16 + lm] =
                    acc[nt][r] + cf[base + nt * 4 + r] + bias;
            }
        }
    }
}

extern "C" void kernel_launch(void* const* d_in, const int* in_sizes, int n_in,
                              void* d_out, int out_size, void* d_ws, size_t ws_size,
                              hipStream_t stream) {
    const float* vals = (const float*)d_in[0];
    const float* keys = (const float*)d_in[1];
    const float* quer = (const float*)d_in[2];
    const int*   mask = (const int*)d_in[3];
    const float* Wv   = (const float*)d_in[4];
    const float* Wo   = (const float*)d_in[5];
    const float* bo   = (const float*)d_in[6];
    float* out = (float*)d_out;

    const size_t N = (size_t)B_ * H_ * S_ * D_;   // 2097152
    ushort_t* ws  = (ushort_t*)d_ws;
    ushort_t* qf  = ws;                 // fp16 (q pre-scaled by log2e)
    ushort_t* kf  = ws + N;             // fp16
    ushort_t* vt  = ws + 2 * N;         // bf16, transposed (bh, d, s)
    ushort_t* ctx = ws + 3 * N;         // bf16
    ushort_t* Wob = ws + 4 * N;         // bf16, 512*512

    proj_mfma<<<dim3(B_ * H_ * (S_ / 64), 4), 256, 0, stream>>>(
        quer, keys, vals, Wv, Wo, qf, kf, vt, Wob);
    attn_mfma<<<B_ * H_ * (S_ / 64), 256, 0, stream>>>(qf, kf, vt, mask, ctx);
    outproj_mfma<<<dim3((B_ * S_) / 64, E_ / 64), 512, 0, stream>>>(ctx, Wob, bo, out);
}

// Round 10
// 125.272 us; speedup vs baseline: 1.6476x; 1.1094x over previous
//
#include <hip/hip_runtime.h>

// MultiHeadSelfAttention  B=2 S=2048 E=512 H=8 D=64, fp32 in/out.
// R16: attn REVERTED to the best-measured config (R11: 512 thr, 8 waves,
//   2-way split-K wave pairs, 46KB LDS, 2 blk/CU, 4 waves/SIMD, named-reg
//   prefetch). Design-space map from R7-R15: every restructure off this
//   point regressed (fat@1blk 66us, no-LDS 120us, fat@2waves/SIMD 53.5us).
//   This round's change: proj simplified to SINGLE-PASS f16 MFMA.
//   Rationale: the 3-term split-bf16 proj computed near-fp32 q/k that were
//   then stored fp16 anyway (2^-11 storage error dominates). f16 inputs ->
//   8 MFMAs (was 24), no split16 (~4x staging VALU cut), LDS 18.4KB.
//   Predicted absmax 0.0156 -> ~0.02-0.03 (threshold 0.094).
//   outproj: unchanged (R9/R11, passed).
// Layouts HW-verified (m89/m91/m120; confirmed R4-R15):
//   A[m=lane&15][k=quad*8+j], B[k=quad*8+j][n=lane&15], D[row=quad*4+reg][col=lane&15].
// LDS stride 72 shorts (144 B) -> 16B-aligned b128, conflict-free (<=2-way).
// Workspace: qf,kf fp16 + vt,ctx bf16 (4 x 4 MB) + Wob (512 KB).

#define B_ 2
#define S_ 2048
#define E_ 512
#define H_ 8
#define D_ 64

#define LOG2E 1.4426950408889634f
#define KEEP_BIAS (-92.332483f)        // -64 * log2(e)

typedef unsigned short ushort_t;
typedef __attribute__((ext_vector_type(8))) short short8;
typedef __attribute__((ext_vector_type(8))) _Float16 half8;
typedef __attribute__((ext_vector_type(4))) float f32x4;

__device__ __forceinline__ ushort_t f2bs(float x) {   // fp32 -> bf16 bits, RNE
    union { float f; unsigned int u; } a; a.f = x;
    unsigned int u = a.u;
    u += 0x7fffu + ((u >> 16) & 1u);
    return (ushort_t)(u >> 16);
}
__device__ __forceinline__ ushort_t f2hs(float x) {   // fp32 -> fp16 bits
    _Float16 h = (_Float16)x;
    ushort_t u; __builtin_memcpy(&u, &h, 2);
    return u;
}

// ---------------- Kernel 1: f16 projection (+ Wob convert) ----------------
// blockIdx.y: 0=q 1=k 2=v 3=Wo->bf16 (bx<128 only).
__global__ void __launch_bounds__(256) proj_mfma(
    const float* __restrict__ quer, const float* __restrict__ keys,
    const float* __restrict__ vals, const float* __restrict__ Wv,
    const float* __restrict__ Wo,
    ushort_t* __restrict__ qf, ushort_t* __restrict__ kf,
    ushort_t* __restrict__ vt, ushort_t* __restrict__ Wob)
{
    __shared__ ushort_t As[64 * 72];      // x tile, f16 [s][d]
    __shared__ ushort_t Bs[64 * 72];      // Wv tile, f16 [e][d]
    const int tens = blockIdx.y;
    const int bx = blockIdx.x;            // bh*32 + st
    const int t = threadIdx.x;

    if (tens == 3) {                      // one-time Wo fp32 -> bf16
        if (bx < 128) {
            int g = (bx * 256 + t) * 8;
            float4 f0 = *(const float4*)(Wo + g);
            float4 f1 = *(const float4*)(Wo + g + 4);
            ushort_t tmp[8] = {f2bs(f0.x), f2bs(f0.y), f2bs(f0.z), f2bs(f0.w),
                               f2bs(f1.x), f2bs(f1.y), f2bs(f1.z), f2bs(f1.w)};
            *(uint4*)&Wob[g] = *(uint4*)tmp;
        }
        return;
    }

    const float* src = tens == 0 ? quer : (tens == 1 ? keys : vals);
    const int st = bx & 31, bh = bx >> 5;
    const int b = bh >> 3, h = bh & 7;
    const int s0 = st * 64;

    {   // Wv -> Bs [e][d] f16   (B[k=d][n=e])
        int e = t >> 2, dg = (t & 3) * 16;
        const float4* g = (const float4*)(Wv + e * 64 + dg);
        ushort_t tmp[16];
        #pragma unroll
        for (int q = 0; q < 4; ++q) {
            float4 f = g[q];
            tmp[q * 4 + 0] = f2hs(f.x); tmp[q * 4 + 1] = f2hs(f.y);
            tmp[q * 4 + 2] = f2hs(f.z); tmp[q * 4 + 3] = f2hs(f.w);
        }
        *(uint4*)&Bs[e * 72 + dg]     = *(uint4*)tmp;
        *(uint4*)&Bs[e * 72 + dg + 8] = *(uint4*)(tmp + 8);
    }
    {   // x rows (s0..s0+63) -> As [s][d] f16
        int row = t >> 2, cg = (t & 3) * 16;
        const float4* g = (const float4*)(src + ((size_t)b * S_ + s0 + row) * 512 + h * 64 + cg);
        ushort_t tmp[16];
        #pragma unroll
        for (int q = 0; q < 4; ++q) {
            float4 f = g[q];
            tmp[q * 4 + 0] = f2hs(f.x); tmp[q * 4 + 1] = f2hs(f.y);
            tmp[q * 4 + 2] = f2hs(f.z); tmp[q * 4 + 3] = f2hs(f.w);
        }
        *(uint4*)&As[row * 72 + cg]     = *(uint4*)tmp;
        *(uint4*)&As[row * 72 + cg + 8] = *(uint4*)(tmp + 8);
    }
    __syncthreads();

    const int w = t >> 6, lm = t & 15, quad = (t >> 4) & 3;
    f32x4 acc[4];
    #pragma unroll
    for (int nt = 0; nt < 4; ++nt) acc[nt] = (f32x4){0.f, 0.f, 0.f, 0.f};

    __builtin_amdgcn_s_setprio(1);
    #pragma unroll
    for (int kk = 0; kk < 2; ++kk) {
        half8 a = *(const half8*)&As[(w * 16 + lm) * 72 + kk * 32 + quad * 8];
        #pragma unroll
        for (int nt = 0; nt < 4; ++nt) {
            half8 bb = *(const half8*)&Bs[(nt * 16 + lm) * 72 + kk * 32 + quad * 8];
            acc[nt] = __builtin_amdgcn_mfma_f32_16x16x32_f16(a, bb, acc[nt], 0, 0, 0);
        }
    }
    __builtin_amdgcn_s_setprio(0);

    if (tens < 2) {       // q,k: store single fp16, layout (bh, s, d); q pre-scaled log2e
        ushort_t* dst = tens == 0 ? qf : kf;
        const float sc = tens == 0 ? LOG2E : 1.0f;
        #pragma unroll
        for (int nt = 0; nt < 4; ++nt) {
            #pragma unroll
            for (int r = 0; r < 4; ++r) {
                size_t addr = ((size_t)bh * S_ + s0 + w * 16 + quad * 4 + r) * 64 + nt * 16 + lm;
                dst[addr] = f2hs(acc[nt][r] * sc);
            }
        }
    } else {              // v: store bf16 transposed (bh, d, s) -> 8B packed stores
        #pragma unroll
        for (int nt = 0; nt < 4; ++nt) {
            unsigned int p0 = (unsigned int)f2bs(acc[nt][0]) | ((unsigned int)f2bs(acc[nt][1]) << 16);
            unsigned int p1 = (unsigned int)f2bs(acc[nt][2]) | ((unsigned int)f2bs(acc[nt][3]) << 16);
            uint2 pk; pk.x = p0; pk.y = p1;
            size_t addr = ((size_t)bh * 64 + nt * 16 + lm) * S_ + s0 + w * 16 + quad * 4;
            *(uint2*)&vt[addr] = pk;
        }
    }
}

// ---------------- Kernel 2: flash attention (split-K wave pairs; R11 verbatim) ----------------
__global__ void __launch_bounds__(512, 4) attn_mfma(
    const ushort_t* __restrict__ qf, const ushort_t* __restrict__ kf,
    const ushort_t* __restrict__ vt, const int* __restrict__ mask,
    ushort_t* __restrict__ ctx)
{
    __shared__ ushort_t Ks[2][64 * 72];       // fp16 K tiles [k][d]: [0]=even kc, [1]=odd kc
    __shared__ ushort_t Vt[2][64 * 72];       // bf16 V tiles [d][k]
    __shared__ ushort_t Ps[8 * 16 * 72];      // per-wave 16x64 P, bf16; reused as f32 combine scratch
    __shared__ float    mb[2][64];            // KEEP_BIAS or -1e30f, per parity

    const int bx = blockIdx.x;
    const int qt = bx & 31;                   // S/64 = 32 q-tiles
    const int bh = bx >> 5;
    const int b  = bh >> 3;
    const int t  = threadIdx.x;
    const int w  = t >> 6;                    // 0..7
    const int wq = w & 3;                     // q-group within the 64-row tile
    const int ws = w >> 2;                    // k-parity this wave computes
    const int lm = t & 15, quad = (t >> 4) & 3;
    const int q0 = qt * 64;
    const int wbase = w * 16 * 72;

    // staging geometry: 512 threads, each one uint4 (8 shorts) per 64x64 tile
    const int srow = t >> 3;                  // 0..63
    const int scg  = (t & 7) * 8;             // 0..56
    const size_t kgbase = ((size_t)bh * S_ + srow) * 64 + scg;    // + kc*4096
    const size_t vgbase = ((size_t)bh * 64 + srow) * S_ + scg;    // + kc*64

    // Q B-frag direct from global fp16 (already scaled by log2e in proj)
    half8 aq[2];
    {
        size_t qrow = ((size_t)bh * S_ + q0 + wq * 16 + lm) * 64 + quad * 8;
        aq[0] = *(const half8*)&qf[qrow];
        aq[1] = *(const half8*)&qf[qrow + 32];
    }
    short8 ones;
    #pragma unroll
    for (int j = 0; j < 8; ++j) ones[j] = (short)0x3F80;   // bf16 1.0

    f32x4 acc[4];
    #pragma unroll
    for (int nt = 0; nt < 4; ++nt) acc[nt] = (f32x4){0.f, 0.f, 0.f, 0.f};
    f32x4 acc_l = (f32x4){0.f, 0.f, 0.f, 0.f};   // row sums l

    // ---- prologue: stage tiles 0 (buf0) and 1 (buf1) ----
    {
        *(uint4*)&Ks[0][srow * 72 + scg] = *(const uint4*)&kf[kgbase];
        *(uint4*)&Ks[1][srow * 72 + scg] = *(const uint4*)&kf[kgbase + 4096];
        *(uint4*)&Vt[0][srow * 72 + scg] = *(const uint4*)&vt[vgbase];
        *(uint4*)&Vt[1][srow * 72 + scg] = *(const uint4*)&vt[vgbase + 64];
        if (t < 128) mb[t >> 6][t & 63] = mask[b * S_ + t] ? KEEP_BIAS : -1e30f;
    }
    __syncthreads();

    for (int is = 0; is < S_ / 128; ++is) {
        const bool pf = (is + 1) < (S_ / 128);

        // ---- prefetch next superstep's two tiles into registers ----
        uint4 pk0, pk1, pv0, pv1; int mnx = 0;
        if (pf) {
            size_t ko = kgbase + (size_t)(2 * (is + 1)) * 4096;
            pk0 = *(const uint4*)&kf[ko];
            pk1 = *(const uint4*)&kf[ko + 4096];
            size_t vo = vgbase + (size_t)(2 * (is + 1)) * 64;
            pv0 = *(const uint4*)&vt[vo];
            pv1 = *(const uint4*)&vt[vo + 64];
            if (t < 128) mnx = mask[b * S_ + (2 * (is + 1)) * 64 + t];
        }

        const ushort_t* Kc = Ks[ws];
        const ushort_t* Vc = Vt[ws];

        // ---- S^T = K Q^T (f16), accumulator INIT = mask bias (f(k) = D-row).
        //      p = exp2(s) (q pre-scaled by log2e); f2bs pack; b64 write per nt. ----
        #pragma unroll
        for (int nt = 0; nt < 4; ++nt) {
            f32x4 s = *(const f32x4*)&mb[ws][nt * 16 + quad * 4];
            __builtin_amdgcn_s_setprio(1);
            #pragma unroll
            for (int kk = 0; kk < 2; ++kk) {
                half8 ak = *(const half8*)&Kc[(nt * 16 + lm) * 72 + kk * 32 + quad * 8];
                s = __builtin_amdgcn_mfma_f32_16x16x32_f16(ak, aq[kk], s, 0, 0, 0);
            }
            __builtin_amdgcn_s_setprio(0);
            float p0 = __builtin_amdgcn_exp2f(s[0]);
            float p1 = __builtin_amdgcn_exp2f(s[1]);
            float p2 = __builtin_amdgcn_exp2f(s[2]);
            float p3 = __builtin_amdgcn_exp2f(s[3]);
            uint2 pkd;
            pkd.x = (unsigned int)f2bs(p0) | ((unsigned int)f2bs(p1) << 16);
            pkd.y = (unsigned int)f2bs(p2) | ((unsigned int)f2bs(p3) << 16);
            *(uint2*)&Ps[wbase + lm * 72 + nt * 16 + quad * 4] = pkd;
        }
        // (no explicit drain: compiler inserts counted lgkmcnt for the in-wave
        //  Ps write->read dependency; independent Vt reads can overlap it)

        // ---- O += P V ; l += P . 1  (bf16 MFMA) ----
        __builtin_amdgcn_s_setprio(1);
        #pragma unroll
        for (int kk = 0; kk < 2; ++kk) {
            short8 ap = *(const short8*)&Ps[wbase + lm * 72 + kk * 32 + quad * 8];
            #pragma unroll
            for (int nt = 0; nt < 4; ++nt) {
                short8 bv = *(const short8*)&Vc[(nt * 16 + lm) * 72 + kk * 32 + quad * 8];
                acc[nt] = __builtin_amdgcn_mfma_f32_16x16x32_bf16(ap, bv, acc[nt], 0, 0, 0);
            }
            acc_l = __builtin_amdgcn_mfma_f32_16x16x32_bf16(ap, ones, acc_l, 0, 0, 0);
        }
        __builtin_amdgcn_s_setprio(0);

        __syncthreads();                       // all waves done reading both buffers
        if (pf) {
            *(uint4*)&Ks[0][srow * 72 + scg] = pk0;
            *(uint4*)&Ks[1][srow * 72 + scg] = pk1;
            *(uint4*)&Vt[0][srow * 72 + scg] = pv0;
            *(uint4*)&Vt[1][srow * 72 + scg] = pv1;
            if (t < 128) mb[t >> 6][t & 63] = mnx ? KEEP_BIAS : -1e30f;
            __syncthreads();                   // staged tiles visible
        }
    }

    // ---- combine split-K halves across wave pairs (fp32, via reused Ps) ----
    float* cf = (float*)Ps;
    const int lane = t & 63;
    __syncthreads();
    if (ws == 1) {       // write O partials: stride 18 floats (bank-skewed, 8B aligned)
        const int base = (wq * 64 + lane) * 18;
        #pragma unroll
        for (int nt = 0; nt < 4; ++nt) {
            #pragma unroll
            for (int r = 0; r < 4; r += 2) {
                float2 v2; v2.x = acc[nt][r]; v2.y = acc[nt][r + 1];
                *(float2*)&cf[base + nt * 4 + r] = v2;
            }
        }
    }
    __syncthreads();
    if (ws == 0) {
        const int base = (wq * 64 + lane) * 18;
        #pragma unroll
        for (int nt = 0; nt < 4; ++nt) {
            #pragma unroll
            for (int r = 0; r < 4; ++r) acc[nt][r] += cf[base + nt * 4 + r];
        }
    }
    __syncthreads();
    if (ws == 1) {       // write l partials: stride 5 floats
        const int base = (wq * 64 + lane) * 5;
        #pragma unroll
        for (int r = 0; r < 4; ++r) cf[base + r] = acc_l[r];
    }
    __syncthreads();

    // ---- finalize (ws==0 waves): ctx[b, s, h*64+d] bf16 ----
    if (ws == 0) {
        const int base = (wq * 64 + lane) * 5;
        #pragma unroll
        for (int r = 0; r < 4; ++r) acc_l[r] += cf[base + r];
        const int h = bh & 7;
        #pragma unroll
        for (int r = 0; r < 4; ++r) {
            float inv = 1.f / acc_l[r];
            int s = q0 + wq * 16 + quad * 4 + r;
            #pragma unroll
            for (int nt = 0; nt < 4; ++nt) {
                int d = nt * 16 + lm;
                ctx[((size_t)b * S_ + s) * E_ + h * D_ + d] = f2bs(acc[nt][r] * inv);
            }
        }
    }
}

// ---------------- Kernel 3: out = ctx @ Wo^T + bo (split-K wave halves) ----------------
__global__ void __launch_bounds__(512, 4) outproj_mfma(
    const ushort_t* __restrict__ ctx, const ushort_t* __restrict__ Wob,
    const float* __restrict__ bo, float* __restrict__ out)
{
    __shared__ ushort_t sm[4][64 * 72];       // A0,A1,B0,B1 ; reused as f32 combine scratch
    const int m0 = blockIdx.x * 64, n0 = blockIdx.y * 64;
    const int t = threadIdx.x;
    const int w = t >> 6, wq = w & 3, wk = w >> 2;
    const int lm = t & 15, quad = (t >> 4) & 3;
    const int srow = t >> 3, scg = (t & 7) * 8;

    const size_t abase = (size_t)(m0 + srow) * E_ + scg;   // + ktile*64
    const size_t bbase = (size_t)(n0 + srow) * E_ + scg;

    f32x4 acc[4];
    #pragma unroll
    for (int nt = 0; nt < 4; ++nt) acc[nt] = (f32x4){0.f, 0.f, 0.f, 0.f};

    // prologue: stage superstep 0 (k-tiles 0 and 4)
    *(uint4*)&sm[0][srow * 72 + scg] = *(const uint4*)&ctx[abase];
    *(uint4*)&sm[1][srow * 72 + scg] = *(const uint4*)&ctx[abase + 256];
    *(uint4*)&sm[2][srow * 72 + scg] = *(const uint4*)&Wob[bbase];
    *(uint4*)&sm[3][srow * 72 + scg] = *(const uint4*)&Wob[bbase + 256];
    __syncthreads();

    const ushort_t* Ac = sm[wk];
    const ushort_t* Bc = sm[2 + wk];

    for (int is = 0; is < 4; ++is) {
        const bool pf = is < 3;
        uint4 pa0, pa1, pb0, pb1;
        if (pf) {
            pa0 = *(const uint4*)&ctx[abase + (size_t)(is + 1) * 64];
            pa1 = *(const uint4*)&ctx[abase + 256 + (size_t)(is + 1) * 64];
            pb0 = *(const uint4*)&Wob[bbase + (size_t)(is + 1) * 64];
            pb1 = *(const uint4*)&Wob[bbase + 256 + (size_t)(is + 1) * 64];
        }

        __builtin_amdgcn_s_setprio(1);
        #pragma unroll
        for (int kk = 0; kk < 2; ++kk) {
            short8 a = *(const short8*)&Ac[(wq * 16 + lm) * 72 + kk * 32 + quad * 8];
            #pragma unroll
            for (int nt = 0; nt < 4; ++nt) {
                short8 bb = *(const short8*)&Bc[(nt * 16 + lm) * 72 + kk * 32 + quad * 8];
                acc[nt] = __builtin_amdgcn_mfma_f32_16x16x32_bf16(a, bb, acc[nt], 0, 0, 0);
            }
        }
        __builtin_amdgcn_s_setprio(0);

        __syncthreads();                       // all waves done reading tiles
        if (pf) {
            *(uint4*)&sm[0][srow * 72 + scg] = pa0;
            *(uint4*)&sm[1][srow * 72 + scg] = pa1;
            *(uint4*)&sm[2][srow * 72 + scg] = pb0;
            *(uint4*)&sm[3][srow * 72 + scg] = pb1;
            __syncthreads();
        }
    }

    // ---- combine k-halves (fp32, reuse sm; 36 KB >= 18.4 KB needed) ----
    float* cf = (float*)sm;
    const int lane = t & 63;
    if (wk == 1) {
        const int base = (wq * 64 + lane) * 18;
        #pragma unroll
        for (int nt = 0; nt < 4; ++nt) {
            #pragma unroll
            for (int r = 0; r < 4; r += 2) {
                float2 v2; v2.x = acc[nt][r]; v2.y = acc[nt][r + 1];
                *(float2*)&cf[base + nt * 4 + r] = v2;
            }
        }
    }
    __syncthreads();
    if (wk == 0) {
        const int base = (wq * 64 + lane) * 18;
        #pragma unroll
        for (int nt = 0; nt < 4; ++nt) {
            float bias = bo[n0 + nt * 16 + lm];
            #pragma unroll
            for (int r = 0; r < 4; ++r) {
                int m = m0 + wq * 16 + quad * 4 + r;
                out[(size_t)m * E_ + n0 + nt * 16 + lm] =
                    acc[nt][r] + cf[base + nt * 4 + r] + bias;
            }
        }
    }
}

extern "C" void kernel_launch(void* const* d_in, const int* in_sizes, int n_in,
                              void* d_out, int out_size, void* d_ws, size_t ws_size,
                              hipStream_t stream) {
    const float* vals = (const float*)d_in[0];
    const float* keys = (const float*)d_in[1];
    const float* quer = (const float*)d_in[2];
    const int*   mask = (const int*)d_in[3];
    const float* Wv   = (const float*)d_in[4];
    const float* Wo   = (const float*)d_in[5];
    const float* bo   = (const float*)d_in[6];
    float* out = (float*)d_out;

    const size_t N = (size_t)B_ * H_ * S_ * D_;   // 2097152
    ushort_t* ws  = (ushort_t*)d_ws;
    ushort_t* qf  = ws;                 // fp16 (q pre-scaled by log2e)
    ushort_t* kf  = ws + N;             // fp16
    ushort_t* vt  = ws + 2 * N;         // bf16, transposed (bh, d, s)
    ushort_t* ctx = ws + 3 * N;         // bf16
    ushort_t* Wob = ws + 4 * N;         // bf16, 512*512

    proj_mfma<<<dim3(B_ * H_ * (S_ / 64), 4), 256, 0, stream>>>(
        quer, keys, vals, Wv, Wo, qf, kf, vt, Wob);
    attn_mfma<<<B_ * H_ * (S_ / 64), 512, 0, stream>>>(qf, kf, vt, mask, ctx);
    outproj_mfma<<<dim3((B_ * S_) / 64, E_ / 64), 512, 0, stream>>>(ctx, Wob, bo, out);
}